// Round 4
// baseline (245.390 us; speedup 1.0000x reference)
//
#include <hip/hip_runtime.h>
#include <hip/hip_bf16.h>

// Problem: lstm_20169166422798
// x:(64,512,513) W_ih:(200,513) W_hh:(200,50) b_ih:(200) b_hh:(200)
// W_out:(513,50) b_out:(513)  -> out:(64,512,513) fp32

#define B_SZ 64
#define T_SZ 512
#define F_SZ 513
#define H_SZ 50
#define G_SZ 200            // 4*H
#define M_SZ (B_SZ * T_SZ)  // 32768

typedef __attribute__((ext_vector_type(8))) short short8;   // bf16x8 MFMA frag
typedef __attribute__((ext_vector_type(4))) float f32x4;    // MFMA acc
typedef __attribute__((ext_vector_type(4), aligned(4))) float f32x4u;  // 4B-aligned vec load
typedef __attribute__((ext_vector_type(2))) float f32x2;    // packed-FMA pair

__device__ __forceinline__ float bf2f(unsigned short u) {
  unsigned int v = ((unsigned int)u) << 16;
  return __builtin_bit_cast(float, v);
}
__device__ __forceinline__ unsigned short f2bf(float f) {
  unsigned int b = __builtin_bit_cast(unsigned int, f);
  unsigned int r = b + 0x7FFFu + ((b >> 16) & 1u);
  return (unsigned short)(r >> 16);
}

// Anti-rematerialization pin: r3's lstm_rec regression root cause was the
// allocator SINKING the loop-invariant Whh loads into the 64-step chain
// (VGPR_Count=152 vs ~280 needed -> ~100 dependent L1/L2 reloads per step).
// Passing each weight pair through an opaque asm makes the value
// non-rematerializable: the compiler must keep it resident in VGPRs.
__device__ __forceinline__ void pin2(f32x2& v) {
  double d = __builtin_bit_cast(double, v);
  asm volatile("" : "+v"(d));
  v = __builtin_bit_cast(f32x2, d);
}
__device__ __forceinline__ void pin1(float& v) { asm volatile("" : "+v"(v)); }

// --------------- K0w: W_ih and W_out -> bf16 MFMA fragments (consumption order)
// Wf_ih[((t*13+nt)*64+lane)] : n=nt*16+(lane&15), k=t*32+(lane>>4)*8+j, t=0..16
// Wf_out[((t*33+nt)*64+lane)]: n=nt*16+(lane&15), k=t*32+(lane>>4)*8+j, t=0..1
#define NF_IH (17 * 13 * 64)
#define NF_OUT (2 * 33 * 64)
__global__ __launch_bounds__(256) void conv_weights(
    const float* __restrict__ Wih, const float* __restrict__ Wout,
    unsigned short* __restrict__ Wf_ih, unsigned short* __restrict__ Wf_out) {
  int idx = blockIdx.x * 256 + threadIdx.x;
  if (idx < NF_IH) {
    int lane = idx & 63;
    int nt = (idx >> 6) % 13;
    int t = idx / (13 * 64);
    int n = nt * 16 + (lane & 15);
    int k0 = t * 32 + (lane >> 4) * 8;
    short8 v;
#pragma unroll
    for (int j = 0; j < 8; j++) {
      int k = k0 + j;
      v[j] = (n < G_SZ && k < F_SZ) ? (short)f2bf(Wih[(size_t)n * F_SZ + k])
                                    : (short)0;
    }
    *(short8*)(Wf_ih + (size_t)idx * 8) = v;
  } else if (idx < NF_IH + NF_OUT) {
    int id2 = idx - NF_IH;
    int lane = id2 & 63;
    int nt = (id2 >> 6) % 33;
    int t = id2 / (33 * 64);
    int n = nt * 16 + (lane & 15);
    int k0 = t * 32 + (lane >> 4) * 8;
    short8 v;
#pragma unroll
    for (int j = 0; j < 8; j++) {
      int k = k0 + j;
      v[j] = (n < F_SZ && k < H_SZ) ? (short)f2bf(Wout[(size_t)n * H_SZ + k])
                                    : (short)0;
    }
    *(short8*)(Wf_out + (size_t)id2 * 8) = v;
  }
}

// ---------------------------------------------------------------- K1: xg GEMM
// xg(32768 x 200, bf16) = x(32768 x 513, fp32, converted in-register) @ W_ih^T
// + b_ih.  Depth-4 named-register slab pipeline + __launch_bounds__(256,2).
// Bounds: xr = row + kg*8 (kg*8 <= 24); max load idx 480+24+7 = 511 < 513.
__global__ __launch_bounds__(256, 2) void gemm_xg_mfma(
    const float* __restrict__ x, const unsigned short* __restrict__ Wf,
    const float* __restrict__ bih, unsigned short* __restrict__ xg) {
  int wave = threadIdx.x >> 6;
  int lane = threadIdx.x & 63;
  int m0 = blockIdx.x * 64 + wave * 16;
  int arow = lane & 15;  // m within tile
  int kg = lane >> 4;

  f32x4 acc[13];
#pragma unroll
  for (int nt = 0; nt < 13; nt++) acc[nt] = (f32x4){0.f, 0.f, 0.f, 0.f};

  const float* xr = x + (size_t)(m0 + arow) * F_SZ + kg * 8;  // lane's k-origin
  const short8* Bf = (const short8*)Wf;

  auto cvt8 = [](f32x4u lo, f32x4u hi) {
    short8 af;
#pragma unroll
    for (int jj = 0; jj < 4; jj++) af[jj] = (short)f2bf(lo[jj]);
#pragma unroll
    for (int jj = 0; jj < 4; jj++) af[4 + jj] = (short)f2bf(hi[jj]);
    return af;
  };
  auto mfma13 = [&](int t, short8 af) {
#pragma unroll
    for (int nt = 0; nt < 13; nt++) {
      short8 bf = Bf[(t * 13 + nt) * 64 + lane];
      acc[nt] = __builtin_amdgcn_mfma_f32_16x16x32_bf16(bf, af, acc[nt], 0, 0, 0);
    }
  };

  // depth-4 slab pipeline: named regs (no runtime indexing -> no scratch)
  f32x4u pa0 = *(const f32x4u*)(xr + 0 * 32), pa1 = *(const f32x4u*)(xr + 0 * 32 + 4);
  f32x4u pb0 = *(const f32x4u*)(xr + 1 * 32), pb1 = *(const f32x4u*)(xr + 1 * 32 + 4);
  f32x4u pc0 = *(const f32x4u*)(xr + 2 * 32), pc1 = *(const f32x4u*)(xr + 2 * 32 + 4);
  f32x4u pd0 = *(const f32x4u*)(xr + 3 * 32), pd1 = *(const f32x4u*)(xr + 3 * 32 + 4);

#pragma unroll
  for (int t = 0; t < 16; t += 4) {
    short8 af = cvt8(pa0, pa1);
    if (t + 4 < 16) { pa0 = *(const f32x4u*)(xr + (t + 4) * 32); pa1 = *(const f32x4u*)(xr + (t + 4) * 32 + 4); }
    mfma13(t, af);

    af = cvt8(pb0, pb1);
    if (t + 5 < 16) { pb0 = *(const f32x4u*)(xr + (t + 5) * 32); pb1 = *(const f32x4u*)(xr + (t + 5) * 32 + 4); }
    mfma13(t + 1, af);

    af = cvt8(pc0, pc1);
    if (t + 6 < 16) { pc0 = *(const f32x4u*)(xr + (t + 6) * 32); pc1 = *(const f32x4u*)(xr + (t + 6) * 32 + 4); }
    mfma13(t + 2, af);

    af = cvt8(pd0, pd1);
    if (t + 7 < 16) { pd0 = *(const f32x4u*)(xr + (t + 7) * 32); pd1 = *(const f32x4u*)(xr + (t + 7) * 32 + 4); }
    mfma13(t + 3, af);
  }

  // tail slab t=16: only k=512 is real (Wf also zero-padded past k=513)
  {
    short8 af = (short8){0, 0, 0, 0, 0, 0, 0, 0};
    if (kg == 0) af[0] = (short)f2bf(xr[512]);  // xr has +kg*8; kg==0 only
    mfma13(16, af);
  }

  unsigned short* xrow = xg + (size_t)(m0 + arow) * G_SZ;
#pragma unroll
  for (int nt = 0; nt < 13; nt++) {
    int nb = nt * 16 + kg * 4;
    if (nt < 12 || kg < 2) {  // n < 200
      float4 bi = *(const float4*)&bih[nb];
      ushort4 o;
      o.x = f2bf(acc[nt][0] + bi.x);
      o.y = f2bf(acc[nt][1] + bi.y);
      o.z = f2bf(acc[nt][2] + bi.z);
      o.w = f2bf(acc[nt][3] + bi.w);
      *(ushort4*)(xrow + nb) = o;
    }
  }
}

// ------------------------------------------------------------- K2: recurrence
__device__ __forceinline__ float sig_f(float v) {
  return 1.0f / (1.0f + __expf(-v));
}
__device__ __forceinline__ float tanh_f(float v) {
  return 2.0f / (1.0f + __expf(-2.0f * v)) - 1.0f;
}

// ONE WAVE per t; lane j owns h_j and computes ALL FOUR gate rows (4 dots of 50
// as packed f32x2 FMA).  No barrier, no gact exchange: the only per-step
// communication is in-wave h ds_write -> uniform-address broadcast ds_read
// (same-wave DS ops process in issue order; compiler inserts lgkmcnt).
// Weights: w2[4][25] f32x2 (200 VGPRs) PINNED via opaque asm so the allocator
// cannot sink the loads into the chain (r3 root cause).  Budget ~310 VGPRs at
// __launch_bounds__(64,1) (512/wave available, spill-free through ~450: m08).
__global__ __launch_bounds__(64, 1) void lstm_rec(
    const unsigned short* __restrict__ xg, const float* __restrict__ Whh,
    const float* __restrict__ bhh, unsigned short* __restrict__ hs_b) {
  int t = blockIdx.x;
  int j = threadIdx.x;                  // 0..63
  int jc = (j < H_SZ) ? j : (H_SZ - 1);
  __shared__ __align__(16) float h_sh[64];

  f32x2 w2[4][25];
  float bh[4];
#pragma unroll
  for (int g = 0; g < 4; g++) {
    const float* wr = Whh + (size_t)(g * H_SZ + jc) * H_SZ;
    bh[g] = bhh[g * H_SZ + jc];
    pin1(bh[g]);
#pragma unroll
    for (int k = 0; k < 25; k++) {
      w2[g][k] = *(const f32x2*)(wr + 2 * k);
      pin2(w2[g][k]);  // non-rematerializable: stays in VGPRs for the kernel
    }
  }

  h_sh[j] = 0.f;
  float c = 0.f;

  const size_t bstr = (size_t)T_SZ * G_SZ;
  const unsigned short* xp = xg + (size_t)t * G_SZ + jc;

  // 8-step-deep xg prefetch: two chunks of 4 steps x 4 gates, named arrays,
  // all indices static after unroll.
  unsigned short rA[16], rB[16];
#pragma unroll
  for (int q = 0; q < 4; q++)
#pragma unroll
    for (int g = 0; g < 4; g++) rA[q * 4 + g] = xp[(size_t)q * bstr + g * H_SZ];
#pragma unroll
  for (int q = 0; q < 4; q++)
#pragma unroll
    for (int g = 0; g < 4; g++) rB[q * 4 + g] = xp[(size_t)(4 + q) * bstr + g * H_SZ];

#pragma unroll 1
  for (int b0 = 0; b0 < B_SZ; b0 += 8) {
    float xfA[16], xfB[16];
#pragma unroll
    for (int q = 0; q < 16; q++) xfA[q] = bf2f(rA[q]);
    if (b0 + 8 < B_SZ) {
#pragma unroll
      for (int q = 0; q < 4; q++)
#pragma unroll
        for (int g = 0; g < 4; g++)
          rA[q * 4 + g] = xp[(size_t)(b0 + 8 + q) * bstr + g * H_SZ];
    }
#pragma unroll
    for (int q = 0; q < 16; q++) xfB[q] = bf2f(rB[q]);
    if (b0 + 12 < B_SZ) {
#pragma unroll
      for (int q = 0; q < 4; q++)
#pragma unroll
        for (int g = 0; g < 4; g++)
          rB[q * 4 + g] = xp[(size_t)(b0 + 12 + q) * bstr + g * H_SZ];
    }

#pragma unroll
    for (int u = 0; u < 8; u++) {
      f32x2 aa[4], ab[4];
#pragma unroll
      for (int g = 0; g < 4; g++) {
        float x0 = (u < 4) ? xfA[u * 4 + g] : xfB[(u - 4) * 4 + g];
        aa[g] = (f32x2){x0 + bh[g], 0.f};
        ab[g] = (f32x2){0.f, 0.f};
      }

      // h broadcast: 12 x b128 + 1 x b64, wave-uniform addresses
      const float4* h4 = (const float4*)h_sh;
#pragma unroll
      for (int kq = 0; kq < 12; kq++) {
        float4 hv = h4[kq];
        f32x2 hlo = (f32x2){hv.x, hv.y};
        f32x2 hhi = (f32x2){hv.z, hv.w};
#pragma unroll
        for (int g = 0; g < 4; g++) {
          aa[g] = __builtin_elementwise_fma(hlo, w2[g][2 * kq], aa[g]);
          ab[g] = __builtin_elementwise_fma(hhi, w2[g][2 * kq + 1], ab[g]);
        }
      }
      {
        f32x2 hl = *(const f32x2*)(h_sh + 48);
#pragma unroll
        for (int g = 0; g < 4; g++)
          aa[g] = __builtin_elementwise_fma(hl, w2[g][24], aa[g]);
      }

      float av0 = (aa[0][0] + ab[0][0]) + (aa[0][1] + ab[0][1]);
      float av1 = (aa[1][0] + ab[1][0]) + (aa[1][1] + ab[1][1]);
      float av2 = (aa[2][0] + ab[2][0]) + (aa[2][1] + ab[2][1]);
      float av3 = (aa[3][0] + ab[3][0]) + (aa[3][1] + ab[3][1]);

      float iv = sig_f(av0);
      float fv = sig_f(av1);
      float gv = tanh_f(av2);
      float ov = sig_f(av3);
      c = fmaf(fv, c, iv * gv);
      float h = ov * tanh_f(c);
      float hval = (j < H_SZ) ? h : 0.f;

      h_sh[j] = hval;  // in-wave DS ordering; no barrier needed
      int b = b0 + u;
      hs_b[((size_t)b * T_SZ + t) * 64 + j] = f2bf(hval);  // zero-padded cols
    }
  }
}

// ------------------------------------------------------------ K3: out GEMM
// out(32768 x 513, fp32) = hs_b(32768 x 64, bf16, k-padded) @ Wout^T + b_out.
__global__ __launch_bounds__(256, 2) void gemm_out_mfma(
    const unsigned short* __restrict__ hs_b,
    const unsigned short* __restrict__ Wf, const float* __restrict__ bout,
    float* __restrict__ out) {
  int wave = threadIdx.x >> 6;
  int lane = threadIdx.x & 63;
  int m0 = blockIdx.x * 64 + wave * 16;
  int arow = lane & 15;  // m within tile
  int kg = lane >> 4;

  const short8* Af = (const short8*)(hs_b + (size_t)(m0 + arow) * 64);
  short8 af0 = Af[kg];      // k = kg*8
  short8 af1 = Af[4 + kg];  // k = 32 + kg*8
  const short8* Bf = (const short8*)Wf;
  float* orow = out + (size_t)(m0 + arow) * F_SZ;

#pragma unroll
  for (int nt = 0; nt < 33; nt++) {
    short8 bf0 = Bf[nt * 64 + lane];
    short8 bf1 = Bf[(33 + nt) * 64 + lane];
    f32x4 acc = (f32x4){0.f, 0.f, 0.f, 0.f};
    acc = __builtin_amdgcn_mfma_f32_16x16x32_bf16(bf0, af0, acc, 0, 0, 0);
    acc = __builtin_amdgcn_mfma_f32_16x16x32_bf16(bf1, af1, acc, 0, 0, 0);
    if (nt < 32) {
      int f0 = nt * 16 + kg * 4;
      float4 bv = *(const float4*)&bout[f0];
      float4 o = make_float4(acc[0] + bv.x, acc[1] + bv.y, acc[2] + bv.z,
                             acc[3] + bv.w);
      *(float4*)(orow + f0) = o;  // rows 4B-aligned; HW handles unaligned x4
    } else if (kg == 0) {
      orow[512] = acc[0] + bout[512];  // nt=32: only f=512 real
    }
  }
}

extern "C" void kernel_launch(void* const* d_in, const int* in_sizes, int n_in,
                              void* d_out, int out_size, void* d_ws,
                              size_t ws_size, hipStream_t stream) {
  const float* x = (const float*)d_in[0];
  const float* Wih = (const float*)d_in[1];
  const float* Whh = (const float*)d_in[2];
  const float* bih = (const float*)d_in[3];
  const float* bhh = (const float*)d_in[4];
  const float* Wout = (const float*)d_in[5];
  const float* bout = (const float*)d_in[6];
  float* out = (float*)d_out;

  // ws layout (17.6 MB):
  //   xg_b   : bf16 [32768][200]   13,107,200 B @ 0
  //   hs_b   : bf16 [32768][64]     4,194,304 B @ 13,107,200
  //   Wf_ih  : 17*13*64 frags         226,304 B @ 17,301,504
  //   Wf_out : 2*33*64 frags           67,584 B @ 17,527,808
  unsigned short* xg_b = (unsigned short*)d_ws;
  unsigned short* hs_b = (unsigned short*)((char*)d_ws + 13107200);
  unsigned short* Wf_ih = (unsigned short*)((char*)d_ws + 17301504);
  unsigned short* Wf_out = (unsigned short*)((char*)d_ws + 17527808);

  conv_weights<<<(NF_IH + NF_OUT + 255) / 256, 256, 0, stream>>>(Wih, Wout,
                                                                 Wf_ih, Wf_out);

  gemm_xg_mfma<<<M_SZ / 64, 256, 0, stream>>>(x, Wf_ih, bih, xg_b);

  lstm_rec<<<T_SZ, 64, 0, stream>>>(xg_b, Whh, bhh, hs_b);

  gemm_out_mfma<<<M_SZ / 64, 256, 0, stream>>>(hs_b, Wf_out, bout, out);
}

// Round 5
// 218.178 us; speedup vs baseline: 1.1247x; 1.1247x over previous
//
#include <hip/hip_runtime.h>
#include <hip/hip_bf16.h>

// Problem: lstm_20169166422798
// x:(64,512,513) W_ih:(200,513) W_hh:(200,50) b_ih:(200) b_hh:(200)
// W_out:(513,50) b_out:(513)  -> out:(64,512,513) fp32

#define B_SZ 64
#define T_SZ 512
#define F_SZ 513
#define H_SZ 50
#define G_SZ 200            // 4*H
#define M_SZ (B_SZ * T_SZ)  // 32768

typedef __attribute__((ext_vector_type(8))) short short8;   // bf16x8 MFMA frag
typedef __attribute__((ext_vector_type(4))) float f32x4;    // MFMA acc
typedef __attribute__((ext_vector_type(4), aligned(4))) float f32x4u;  // 4B-aligned vec load
typedef __attribute__((ext_vector_type(2))) float f32x2;    // packed-FMA pair

__device__ __forceinline__ float bf2f(unsigned short u) {
  unsigned int v = ((unsigned int)u) << 16;
  return __builtin_bit_cast(float, v);
}
__device__ __forceinline__ unsigned short f2bf(float f) {
  unsigned int b = __builtin_bit_cast(unsigned int, f);
  unsigned int r = b + 0x7FFFu + ((b >> 16) & 1u);
  return (unsigned short)(r >> 16);
}

// Anti-rematerialization pin (r3/r4 lesson): without this, the allocator sinks
// the loop-invariant Whh gathers into the 64-step chain (r1: VGPR_Count=44
// with w[50] "live" -> ~50 scattered per-lane reloads per step, only ~8 in
// flight -> the dominant stall).  r4 proved the pin keeps values resident
// (VGPR 152->248).  r4 ALSO proved the one-wave-all-gates design can't fit:
// 200 weight regs against the 256-addressable-VGPR cap left no scheduling
// registers -> LDS reads serialized.  Hence: 4-wave structure + pin.
__device__ __forceinline__ void pin2(f32x2& v) {
  double d = __builtin_bit_cast(double, v);
  asm volatile("" : "+v"(d));
  v = __builtin_bit_cast(f32x2, d);
}
__device__ __forceinline__ void pin1(float& v) { asm volatile("" : "+v"(v)); }

// --------------- K0w: W_ih and W_out -> bf16 MFMA fragments (consumption order)
// Wf_ih[((t*13+nt)*64+lane)] : n=nt*16+(lane&15), k=t*32+(lane>>4)*8+j, t=0..16
// Wf_out[((t*33+nt)*64+lane)]: n=nt*16+(lane&15), k=t*32+(lane>>4)*8+j, t=0..1
#define NF_IH (17 * 13 * 64)
#define NF_OUT (2 * 33 * 64)
__global__ __launch_bounds__(256) void conv_weights(
    const float* __restrict__ Wih, const float* __restrict__ Wout,
    unsigned short* __restrict__ Wf_ih, unsigned short* __restrict__ Wf_out) {
  int idx = blockIdx.x * 256 + threadIdx.x;
  if (idx < NF_IH) {
    int lane = idx & 63;
    int nt = (idx >> 6) % 13;
    int t = idx / (13 * 64);
    int n = nt * 16 + (lane & 15);
    int k0 = t * 32 + (lane >> 4) * 8;
    short8 v;
#pragma unroll
    for (int j = 0; j < 8; j++) {
      int k = k0 + j;
      v[j] = (n < G_SZ && k < F_SZ) ? (short)f2bf(Wih[(size_t)n * F_SZ + k])
                                    : (short)0;
    }
    *(short8*)(Wf_ih + (size_t)idx * 8) = v;
  } else if (idx < NF_IH + NF_OUT) {
    int id2 = idx - NF_IH;
    int lane = id2 & 63;
    int nt = (id2 >> 6) % 33;
    int t = id2 / (33 * 64);
    int n = nt * 16 + (lane & 15);
    int k0 = t * 32 + (lane >> 4) * 8;
    short8 v;
#pragma unroll
    for (int j = 0; j < 8; j++) {
      int k = k0 + j;
      v[j] = (n < F_SZ && k < H_SZ) ? (short)f2bf(Wout[(size_t)n * H_SZ + k])
                                    : (short)0;
    }
    *(short8*)(Wf_out + (size_t)id2 * 8) = v;
  }
}

// ---------------------------------------------------------------- K1: xg GEMM
// xg(32768 x 200, bf16) = x(32768 x 513, fp32, converted in-register) @ W_ih^T
// + b_ih.  Depth-4 named-register slab pipeline + __launch_bounds__(256,2).
// Bounds: xr = row + kg*8 (kg*8 <= 24); max load idx 480+24+7 = 511 < 513.
__global__ __launch_bounds__(256, 2) void gemm_xg_mfma(
    const float* __restrict__ x, const unsigned short* __restrict__ Wf,
    const float* __restrict__ bih, unsigned short* __restrict__ xg) {
  int wave = threadIdx.x >> 6;
  int lane = threadIdx.x & 63;
  int m0 = blockIdx.x * 64 + wave * 16;
  int arow = lane & 15;  // m within tile
  int kg = lane >> 4;

  f32x4 acc[13];
#pragma unroll
  for (int nt = 0; nt < 13; nt++) acc[nt] = (f32x4){0.f, 0.f, 0.f, 0.f};

  const float* xr = x + (size_t)(m0 + arow) * F_SZ + kg * 8;  // lane's k-origin
  const short8* Bf = (const short8*)Wf;

  auto cvt8 = [](f32x4u lo, f32x4u hi) {
    short8 af;
#pragma unroll
    for (int jj = 0; jj < 4; jj++) af[jj] = (short)f2bf(lo[jj]);
#pragma unroll
    for (int jj = 0; jj < 4; jj++) af[4 + jj] = (short)f2bf(hi[jj]);
    return af;
  };
  auto mfma13 = [&](int t, short8 af) {
#pragma unroll
    for (int nt = 0; nt < 13; nt++) {
      short8 bf = Bf[(t * 13 + nt) * 64 + lane];
      acc[nt] = __builtin_amdgcn_mfma_f32_16x16x32_bf16(bf, af, acc[nt], 0, 0, 0);
    }
  };

  // depth-4 slab pipeline: named regs (no runtime indexing -> no scratch)
  f32x4u pa0 = *(const f32x4u*)(xr + 0 * 32), pa1 = *(const f32x4u*)(xr + 0 * 32 + 4);
  f32x4u pb0 = *(const f32x4u*)(xr + 1 * 32), pb1 = *(const f32x4u*)(xr + 1 * 32 + 4);
  f32x4u pc0 = *(const f32x4u*)(xr + 2 * 32), pc1 = *(const f32x4u*)(xr + 2 * 32 + 4);
  f32x4u pd0 = *(const f32x4u*)(xr + 3 * 32), pd1 = *(const f32x4u*)(xr + 3 * 32 + 4);

#pragma unroll
  for (int t = 0; t < 16; t += 4) {
    short8 af = cvt8(pa0, pa1);
    if (t + 4 < 16) { pa0 = *(const f32x4u*)(xr + (t + 4) * 32); pa1 = *(const f32x4u*)(xr + (t + 4) * 32 + 4); }
    mfma13(t, af);

    af = cvt8(pb0, pb1);
    if (t + 5 < 16) { pb0 = *(const f32x4u*)(xr + (t + 5) * 32); pb1 = *(const f32x4u*)(xr + (t + 5) * 32 + 4); }
    mfma13(t + 1, af);

    af = cvt8(pc0, pc1);
    if (t + 6 < 16) { pc0 = *(const f32x4u*)(xr + (t + 6) * 32); pc1 = *(const f32x4u*)(xr + (t + 6) * 32 + 4); }
    mfma13(t + 2, af);

    af = cvt8(pd0, pd1);
    if (t + 7 < 16) { pd0 = *(const f32x4u*)(xr + (t + 7) * 32); pd1 = *(const f32x4u*)(xr + (t + 7) * 32 + 4); }
    mfma13(t + 3, af);
  }

  // tail slab t=16: only k=512 is real (Wf also zero-padded past k=513)
  {
    short8 af = (short8){0, 0, 0, 0, 0, 0, 0, 0};
    if (kg == 0) af[0] = (short)f2bf(xr[512]);  // xr has +kg*8; kg==0 only
    mfma13(16, af);
  }

  unsigned short* xrow = xg + (size_t)(m0 + arow) * G_SZ;
#pragma unroll
  for (int nt = 0; nt < 13; nt++) {
    int nb = nt * 16 + kg * 4;
    if (nt < 12 || kg < 2) {  // n < 200
      float4 bi = *(const float4*)&bih[nb];
      ushort4 o;
      o.x = f2bf(acc[nt][0] + bi.x);
      o.y = f2bf(acc[nt][1] + bi.y);
      o.z = f2bf(acc[nt][2] + bi.z);
      o.w = f2bf(acc[nt][3] + bi.w);
      *(ushort4*)(xrow + nb) = o;
    }
  }
}

// ------------------------------------------------------------- K2: recurrence
__device__ __forceinline__ float sig_f(float v) {
  return 1.0f / (1.0f + __expf(-v));
}
__device__ __forceinline__ float tanh_f(float v) {
  return 2.0f / (1.0f + __expf(-2.0f * v)) - 1.0f;
}

// 4-WAVE structure (proven r0/r1: one 256-thread block per t, wave g owns gate
// g) + PINNED packed weights (r4 lesson).  Per-wave footprint: 50 weight VGPRs
// + ~60 working -- fits easily under the 256-addressable cap, 2 blocks/CU =
// 2 waves/SIMD for latency hiding.  Dot is 25 v_pk_fma_f32 (was 50 scalar).
// ONE barrier per step: h_s per-wave private (redundant identical cell update
// in every wave), gact double-buffered by step parity (a wave can't lap
// another past 2 barriers -> buffer reuse race-free; invariant from r0/r1).
// 8-step-deep xg prefetch, statically indexed.
__global__ __launch_bounds__(256, 2) void lstm_rec(
    const unsigned short* __restrict__ xg, const float* __restrict__ Whh,
    const float* __restrict__ bhh, unsigned short* __restrict__ hs_b) {
  int t = blockIdx.x;
  int g = threadIdx.x >> 6;   // gate 0..3 (i,f,g,o)
  int j = threadIdx.x & 63;
  int jc = (j < H_SZ) ? j : (H_SZ - 1);
  __shared__ __align__(16) float h_s[4][64];     // per-wave private h copy
  __shared__ __align__(16) float gact[2][4][64]; // double-buffered activations

  int grow = g * H_SZ + jc;
  float bh = bhh[grow];
  pin1(bh);
  f32x2 w2[25];
#pragma unroll
  for (int k = 0; k < 25; k++) {
    w2[k] = *(const f32x2*)(Whh + (size_t)grow * H_SZ + 2 * k);
    pin2(w2[k]);  // non-rematerializable: resident for all 64 steps
  }

  h_s[g][j] = 0.f;
  float c = 0.f;

  const size_t bstr = (size_t)T_SZ * G_SZ;
  const unsigned short* xp = xg + (size_t)t * G_SZ + grow;

  // 8-step-deep prefetch of this wave's gate stream (1 ushort per step)
  unsigned short rA[4], rB[4];
#pragma unroll
  for (int q = 0; q < 4; q++) rA[q] = xp[(size_t)q * bstr];
#pragma unroll
  for (int q = 0; q < 4; q++) rB[q] = xp[(size_t)(4 + q) * bstr];

#pragma unroll 1
  for (int b0 = 0; b0 < B_SZ; b0 += 8) {
    float xf[8];
#pragma unroll
    for (int q = 0; q < 4; q++) xf[q] = bf2f(rA[q]);
    if (b0 + 8 < B_SZ) {
#pragma unroll
      for (int q = 0; q < 4; q++) rA[q] = xp[(size_t)(b0 + 8 + q) * bstr];
    }
#pragma unroll
    for (int q = 0; q < 4; q++) xf[4 + q] = bf2f(rB[q]);
    if (b0 + 12 < B_SZ) {
#pragma unroll
      for (int q = 0; q < 4; q++) rB[q] = xp[(size_t)(b0 + 12 + q) * bstr];
    }

#pragma unroll
    for (int u = 0; u < 8; u++) {  // static u: xf index and gact parity fold
      f32x2 aa = (f32x2){xf[u] + bh, 0.f};
      f32x2 ab = (f32x2){0.f, 0.f};

      // h broadcast: 12 x b128 + 1 x b64, wave-uniform addresses
      const float4* h4 = (const float4*)h_s[g];
#pragma unroll
      for (int kq = 0; kq < 12; kq++) {
        float4 hv = h4[kq];
        aa = __builtin_elementwise_fma((f32x2){hv.x, hv.y}, w2[2 * kq], aa);
        ab = __builtin_elementwise_fma((f32x2){hv.z, hv.w}, w2[2 * kq + 1], ab);
      }
      {
        f32x2 hl = *(const f32x2*)(h_s[g] + 48);
        aa = __builtin_elementwise_fma(hl, w2[24], aa);
      }
      float av = (aa[0] + ab[0]) + (aa[1] + ab[1]);

      gact[u & 1][g][j] = (g == 2) ? tanh_f(av) : sig_f(av);
      __syncthreads();  // the only barrier per step

      float iv = gact[u & 1][0][jc];
      float fv = gact[u & 1][1][jc];
      float gv = gact[u & 1][2][jc];
      float ov = gact[u & 1][3][jc];
      c = fmaf(fv, c, iv * gv);
      float h = ov * tanh_f(c);
      float hval = (j < H_SZ) ? h : 0.f;

      h_s[g][j] = hval;  // own copy; in-wave DS ordering only
      if (g == 1)
        hs_b[((size_t)(b0 + u) * T_SZ + t) * 64 + j] = f2bf(hval);
    }
  }
}

// ------------------------------------------------------------ K3: out GEMM
// out(32768 x 513, fp32) = hs_b(32768 x 64, bf16, k-padded) @ Wout^T + b_out.
__global__ __launch_bounds__(256, 2) void gemm_out_mfma(
    const unsigned short* __restrict__ hs_b,
    const unsigned short* __restrict__ Wf, const float* __restrict__ bout,
    float* __restrict__ out) {
  int wave = threadIdx.x >> 6;
  int lane = threadIdx.x & 63;
  int m0 = blockIdx.x * 64 + wave * 16;
  int arow = lane & 15;  // m within tile
  int kg = lane >> 4;

  const short8* Af = (const short8*)(hs_b + (size_t)(m0 + arow) * 64);
  short8 af0 = Af[kg];      // k = kg*8
  short8 af1 = Af[4 + kg];  // k = 32 + kg*8
  const short8* Bf = (const short8*)Wf;
  float* orow = out + (size_t)(m0 + arow) * F_SZ;

#pragma unroll
  for (int nt = 0; nt < 33; nt++) {
    short8 bf0 = Bf[nt * 64 + lane];
    short8 bf1 = Bf[(33 + nt) * 64 + lane];
    f32x4 acc = (f32x4){0.f, 0.f, 0.f, 0.f};
    acc = __builtin_amdgcn_mfma_f32_16x16x32_bf16(bf0, af0, acc, 0, 0, 0);
    acc = __builtin_amdgcn_mfma_f32_16x16x32_bf16(bf1, af1, acc, 0, 0, 0);
    if (nt < 32) {
      int f0 = nt * 16 + kg * 4;
      float4 bv = *(const float4*)&bout[f0];
      float4 o = make_float4(acc[0] + bv.x, acc[1] + bv.y, acc[2] + bv.z,
                             acc[3] + bv.w);
      *(float4*)(orow + f0) = o;  // rows 4B-aligned; HW handles unaligned x4
    } else if (kg == 0) {
      orow[512] = acc[0] + bout[512];  // nt=32: only f=512 real
    }
  }
}

extern "C" void kernel_launch(void* const* d_in, const int* in_sizes, int n_in,
                              void* d_out, int out_size, void* d_ws,
                              size_t ws_size, hipStream_t stream) {
  const float* x = (const float*)d_in[0];
  const float* Wih = (const float*)d_in[1];
  const float* Whh = (const float*)d_in[2];
  const float* bih = (const float*)d_in[3];
  const float* bhh = (const float*)d_in[4];
  const float* Wout = (const float*)d_in[5];
  const float* bout = (const float*)d_in[6];
  float* out = (float*)d_out;

  // ws layout (17.6 MB):
  //   xg_b   : bf16 [32768][200]   13,107,200 B @ 0
  //   hs_b   : bf16 [32768][64]     4,194,304 B @ 13,107,200
  //   Wf_ih  : 17*13*64 frags         226,304 B @ 17,301,504
  //   Wf_out : 2*33*64 frags           67,584 B @ 17,527,808
  unsigned short* xg_b = (unsigned short*)d_ws;
  unsigned short* hs_b = (unsigned short*)((char*)d_ws + 13107200);
  unsigned short* Wf_ih = (unsigned short*)((char*)d_ws + 17301504);
  unsigned short* Wf_out = (unsigned short*)((char*)d_ws + 17527808);

  conv_weights<<<(NF_IH + NF_OUT + 255) / 256, 256, 0, stream>>>(Wih, Wout,
                                                                 Wf_ih, Wf_out);

  gemm_xg_mfma<<<M_SZ / 64, 256, 0, stream>>>(x, Wf_ih, bih, xg_b);

  lstm_rec<<<T_SZ, 256, 0, stream>>>(xg_b, Whh, bhh, hs_b);

  gemm_out_mfma<<<M_SZ / 64, 256, 0, stream>>>(hs_b, Wf_out, bout, out);
}

// Round 6
// 204.989 us; speedup vs baseline: 1.1971x; 1.0643x over previous
//
#include <hip/hip_runtime.h>
#include <hip/hip_bf16.h>

// Problem: lstm_20169166422798
// x:(64,512,513) W_ih:(200,513) W_hh:(200,50) b_ih:(200) b_hh:(200)
// W_out:(513,50) b_out:(513)  -> out:(64,512,513) fp32

#define B_SZ 64
#define T_SZ 512
#define F_SZ 513
#define H_SZ 50
#define G_SZ 200            // 4*H
#define M_SZ (B_SZ * T_SZ)  // 32768

typedef __attribute__((ext_vector_type(8))) short short8;   // bf16x8 MFMA frag
typedef __attribute__((ext_vector_type(4))) float f32x4;    // MFMA acc
typedef __attribute__((ext_vector_type(4), aligned(4))) float f32x4u;  // 4B-aligned vec load
typedef __attribute__((ext_vector_type(2))) float f32x2;    // packed-FMA pair

__device__ __forceinline__ float bf2f(unsigned short u) {
  unsigned int v = ((unsigned int)u) << 16;
  return __builtin_bit_cast(float, v);
}
__device__ __forceinline__ unsigned short f2bf(float f) {
  unsigned int b = __builtin_bit_cast(unsigned int, f);
  unsigned int r = b + 0x7FFFu + ((b >> 16) & 1u);
  return (unsigned short)(r >> 16);
}

// Anti-rematerialization pin (r3/r4): keeps loop-invariant weights resident
// (VGPR or AGPR) instead of letting the allocator sink the gathers into the
// 64-step recurrence.
__device__ __forceinline__ void pin2(f32x2& v) {
  double d = __builtin_bit_cast(double, v);
  asm volatile("" : "+v"(d));
  v = __builtin_bit_cast(f32x2, d);
}
__device__ __forceinline__ void pin1(float& v) { asm volatile("" : "+v"(v)); }

// async global->LDS, 16B per lane; LDS dest = wave-uniform base + lane*16.
__device__ __forceinline__ void gll16(const void* g, void* l) {
  __builtin_amdgcn_global_load_lds(
      (const __attribute__((address_space(1))) unsigned int*)g,
      (__attribute__((address_space(3))) unsigned int*)l, 16, 0, 0);
}

// --------------- K0w: W_ih and W_out -> bf16 MFMA fragments (consumption order)
// Wf_ih[((t*13+nt)*64+lane)] : n=nt*16+(lane&15), k=t*32+(lane>>4)*8+j, t=0..16
// Wf_out[((t*33+nt)*64+lane)]: n=nt*16+(lane&15), k=t*32+(lane>>4)*8+j, t=0..1
#define NF_IH (17 * 13 * 64)
#define NF_OUT (2 * 33 * 64)
__global__ __launch_bounds__(256) void conv_weights(
    const float* __restrict__ Wih, const float* __restrict__ Wout,
    unsigned short* __restrict__ Wf_ih, unsigned short* __restrict__ Wf_out) {
  int idx = blockIdx.x * 256 + threadIdx.x;
  if (idx < NF_IH) {
    int lane = idx & 63;
    int nt = (idx >> 6) % 13;
    int t = idx / (13 * 64);
    int n = nt * 16 + (lane & 15);
    int k0 = t * 32 + (lane >> 4) * 8;
    short8 v;
#pragma unroll
    for (int j = 0; j < 8; j++) {
      int k = k0 + j;
      v[j] = (n < G_SZ && k < F_SZ) ? (short)f2bf(Wih[(size_t)n * F_SZ + k])
                                    : (short)0;
    }
    *(short8*)(Wf_ih + (size_t)idx * 8) = v;
  } else if (idx < NF_IH + NF_OUT) {
    int id2 = idx - NF_IH;
    int lane = id2 & 63;
    int nt = (id2 >> 6) % 33;
    int t = id2 / (33 * 64);
    int n = nt * 16 + (lane & 15);
    int k0 = t * 32 + (lane >> 4) * 8;
    short8 v;
#pragma unroll
    for (int j = 0; j < 8; j++) {
      int k = k0 + j;
      v[j] = (n < F_SZ && k < H_SZ) ? (short)f2bf(Wout[(size_t)n * H_SZ + k])
                                    : (short)0;
    }
    *(short8*)(Wf_out + (size_t)id2 * 8) = v;
  }
}

// ---------------------------------------------------------------- K1: xg GEMM
// xg(32768 x 200, bf16) = x(32768 x 513, fp32, cvt in-register) @ W_ih^T + bih.
// r5 post-mortem: per-wave Bf register loads serialized (~221 L2 loads just-in-
// time, VGPR=56) AND 4x redundant L2 traffic.  Fix: double-buffered LDS staging
// of the 13,312 B/t Wf slab via global_load_lds, shared by all 4 waves; one
// __syncthreads per t (its implicit vmcnt/lgkm drain is the synchronization);
// x slab prefetched one iteration ahead in registers.
// ds_read pattern bb[nt*64+lane] is lane-contiguous 16B -> 2-way bank = free.
#define TSLAB 13312  // 13 frags * 64 lanes * 16B
__global__ __launch_bounds__(256, 2) void gemm_xg_mfma(
    const float* __restrict__ x, const unsigned short* __restrict__ Wf,
    const float* __restrict__ bih, unsigned short* __restrict__ xg) {
  int tid = threadIdx.x;
  int wave = tid >> 6;
  int lane = tid & 63;
  int m0 = blockIdx.x * 64 + wave * 16;
  int arow = lane & 15;  // m within tile
  int kg = lane >> 4;
  __shared__ __align__(16) unsigned short bbuf[2][TSLAB / 2];

  f32x4 acc[13];
#pragma unroll
  for (int nt = 0; nt < 13; nt++) acc[nt] = (f32x4){0.f, 0.f, 0.f, 0.f};

  const float* xr = x + (size_t)(m0 + arow) * F_SZ + kg * 8;  // lane's k-origin

  auto stage = [&](int pb, int t) {
    const char* src = (const char*)Wf + (size_t)t * TSLAB;
    char* dst = (char*)&bbuf[pb][0];
    // 3 full 4096B rounds (all 256 threads) + 1024B tail (wave 0 only)
    gll16(src + 0 * 4096 + tid * 16, dst + 0 * 4096 + wave * 1024);
    gll16(src + 1 * 4096 + tid * 16, dst + 1 * 4096 + wave * 1024);
    gll16(src + 2 * 4096 + tid * 16, dst + 2 * 4096 + wave * 1024);
    if (wave == 0) gll16(src + 12288 + lane * 16, dst + 12288);
  };
  auto cvt8 = [](f32x4u lo, f32x4u hi) {
    short8 af;
#pragma unroll
    for (int jj = 0; jj < 4; jj++) af[jj] = (short)f2bf(lo[jj]);
#pragma unroll
    for (int jj = 0; jj < 4; jj++) af[4 + jj] = (short)f2bf(hi[jj]);
    return af;
  };

  // prologue: stage t=0, load x slab 0
  stage(0, 0);
  f32x4u cx0 = *(const f32x4u*)(xr);
  f32x4u cx1 = *(const f32x4u*)(xr + 4);
  __syncthreads();  // implicit vmcnt(0) drain -> staging + x slab ready

  f32x4u nx0 = cx0, nx1 = cx1;
#pragma unroll 1
  for (int t = 0; t < 16; ++t) {
    int pb = t & 1;
    stage(pb ^ 1, t + 1);  // async: drained by the barrier at loop end
    if (t < 15) {          // x slab t+1 (slab 16 is the scalar tail)
      nx0 = *(const f32x4u*)(xr + (t + 1) * 32);
      nx1 = *(const f32x4u*)(xr + (t + 1) * 32 + 4);
    }
    short8 af = cvt8(cx0, cx1);
    const short8* bb = (const short8*)&bbuf[pb][0];
#pragma unroll
    for (int nt = 0; nt < 13; nt++) {
      short8 bf = bb[nt * 64 + lane];
      acc[nt] = __builtin_amdgcn_mfma_f32_16x16x32_bf16(bf, af, acc[nt], 0, 0, 0);
    }
    cx0 = nx0; cx1 = nx1;
    __syncthreads();  // staging(t+1) complete; buffer pb free for reuse
  }
  // epilogue t=16: only k=512 real (Wf zero-padded past 513); staged in bbuf[0]
  {
    short8 af = (short8){0, 0, 0, 0, 0, 0, 0, 0};
    if (kg == 0) af[0] = (short)f2bf(xr[512]);  // xr has +kg*8; kg==0 only
    const short8* bb = (const short8*)&bbuf[0][0];
#pragma unroll
    for (int nt = 0; nt < 13; nt++) {
      short8 bf = bb[nt * 64 + lane];
      acc[nt] = __builtin_amdgcn_mfma_f32_16x16x32_bf16(bf, af, acc[nt], 0, 0, 0);
    }
  }

  unsigned short* xrow = xg + (size_t)(m0 + arow) * G_SZ;
#pragma unroll
  for (int nt = 0; nt < 13; nt++) {
    int nb = nt * 16 + kg * 4;
    if (nt < 12 || kg < 2) {  // n < 200
      float4 bi = *(const float4*)&bih[nb];
      ushort4 o;
      o.x = f2bf(acc[nt][0] + bi.x);
      o.y = f2bf(acc[nt][1] + bi.y);
      o.z = f2bf(acc[nt][2] + bi.z);
      o.w = f2bf(acc[nt][3] + bi.w);
      *(ushort4*)(xrow + nb) = o;
    }
  }
}

// ------------------------------------------------------------- K2: recurrence
__device__ __forceinline__ float sig_f(float v) {
  return 1.0f / (1.0f + __expf(-v));
}
__device__ __forceinline__ float tanh_f(float v) {
  return 2.0f / (1.0f + __expf(-2.0f * v)) - 1.0f;
}

// 4-wave structure + pinned packed weights (r5) + TWO interleaved recurrences
// per block (t = 2*bid, 2*bid+1).  The A/B streams share the same weights and
// barrier; their independent dot chains, LDS round-trips and exp chains hide
// each other inside the wave (r5 showed ~1760 cyc/step, ~3x the dependent
// path -- the slack is pure latency that a second in-wave stream can fill).
// Grid 256 = 1 block/CU.  One barrier per step covers both streams; gact
// double-buffered by parity (wave can't lap past 2 barriers -> race-free).
__global__ __launch_bounds__(256, 2) void lstm_rec(
    const unsigned short* __restrict__ xg, const float* __restrict__ Whh,
    const float* __restrict__ bhh, unsigned short* __restrict__ hs_b) {
  int tA = blockIdx.x * 2;
  int tB = tA + 1;
  int g = threadIdx.x >> 6;   // gate 0..3 (i,f,g,o)
  int j = threadIdx.x & 63;
  int jc = (j < H_SZ) ? j : (H_SZ - 1);
  __shared__ __align__(16) float hA_s[4][64], hB_s[4][64];   // per-wave h copies
  __shared__ __align__(16) float gactA[2][4][64], gactB[2][4][64];

  int grow = g * H_SZ + jc;
  float bh = bhh[grow];
  pin1(bh);
  f32x2 w2[25];
#pragma unroll
  for (int k = 0; k < 25; k++) {
    w2[k] = *(const f32x2*)(Whh + (size_t)grow * H_SZ + 2 * k);
    pin2(w2[k]);  // non-rematerializable: resident for all 64 steps
  }

  hA_s[g][j] = 0.f;
  hB_s[g][j] = 0.f;
  float cA = 0.f, cB = 0.f;

  const size_t bstr = (size_t)T_SZ * G_SZ;
  const unsigned short* xpA = xg + (size_t)tA * G_SZ + grow;
  const unsigned short* xpB = xg + (size_t)tB * G_SZ + grow;

  // 8-step-deep prefetch per stream (1 ushort per step per stream)
  unsigned short rA0[4], rA1[4], rB0[4], rB1[4];
#pragma unroll
  for (int q = 0; q < 4; q++) { rA0[q] = xpA[(size_t)q * bstr]; rB0[q] = xpB[(size_t)q * bstr]; }
#pragma unroll
  for (int q = 0; q < 4; q++) { rA1[q] = xpA[(size_t)(4 + q) * bstr]; rB1[q] = xpB[(size_t)(4 + q) * bstr]; }

#pragma unroll 1
  for (int b0 = 0; b0 < B_SZ; b0 += 8) {
    float xfA[8], xfB[8];
#pragma unroll
    for (int q = 0; q < 4; q++) { xfA[q] = bf2f(rA0[q]); xfB[q] = bf2f(rB0[q]); }
    if (b0 + 8 < B_SZ) {
#pragma unroll
      for (int q = 0; q < 4; q++) {
        rA0[q] = xpA[(size_t)(b0 + 8 + q) * bstr];
        rB0[q] = xpB[(size_t)(b0 + 8 + q) * bstr];
      }
    }
#pragma unroll
    for (int q = 0; q < 4; q++) { xfA[4 + q] = bf2f(rA1[q]); xfB[4 + q] = bf2f(rB1[q]); }
    if (b0 + 12 < B_SZ) {
#pragma unroll
      for (int q = 0; q < 4; q++) {
        rA1[q] = xpA[(size_t)(b0 + 12 + q) * bstr];
        rB1[q] = xpB[(size_t)(b0 + 12 + q) * bstr];
      }
    }

#pragma unroll
    for (int u = 0; u < 8; u++) {  // static u: xf index and gact parity fold
      f32x2 aaA = (f32x2){xfA[u] + bh, 0.f}, abA = (f32x2){0.f, 0.f};
      f32x2 aaB = (f32x2){xfB[u] + bh, 0.f}, abB = (f32x2){0.f, 0.f};

      const float4* h4A = (const float4*)hA_s[g];
      const float4* h4B = (const float4*)hB_s[g];
#pragma unroll
      for (int kq = 0; kq < 12; kq++) {
        float4 hvA = h4A[kq];
        float4 hvB = h4B[kq];
        aaA = __builtin_elementwise_fma((f32x2){hvA.x, hvA.y}, w2[2 * kq], aaA);
        abA = __builtin_elementwise_fma((f32x2){hvA.z, hvA.w}, w2[2 * kq + 1], abA);
        aaB = __builtin_elementwise_fma((f32x2){hvB.x, hvB.y}, w2[2 * kq], aaB);
        abB = __builtin_elementwise_fma((f32x2){hvB.z, hvB.w}, w2[2 * kq + 1], abB);
      }
      {
        f32x2 hlA = *(const f32x2*)(hA_s[g] + 48);
        f32x2 hlB = *(const f32x2*)(hB_s[g] + 48);
        aaA = __builtin_elementwise_fma(hlA, w2[24], aaA);
        aaB = __builtin_elementwise_fma(hlB, w2[24], aaB);
      }
      float avA = (aaA[0] + abA[0]) + (aaA[1] + abA[1]);
      float avB = (aaB[0] + abB[0]) + (aaB[1] + abB[1]);

      gactA[u & 1][g][j] = (g == 2) ? tanh_f(avA) : sig_f(avA);
      gactB[u & 1][g][j] = (g == 2) ? tanh_f(avB) : sig_f(avB);
      __syncthreads();  // the only barrier per step (covers both streams)

      float ivA = gactA[u & 1][0][jc], fvA = gactA[u & 1][1][jc];
      float gvA = gactA[u & 1][2][jc], ovA = gactA[u & 1][3][jc];
      float ivB = gactB[u & 1][0][jc], fvB = gactB[u & 1][1][jc];
      float gvB = gactB[u & 1][2][jc], ovB = gactB[u & 1][3][jc];
      cA = fmaf(fvA, cA, ivA * gvA);
      cB = fmaf(fvB, cB, ivB * gvB);
      float hA = ovA * tanh_f(cA);
      float hB = ovB * tanh_f(cB);
      float hvalA = (j < H_SZ) ? hA : 0.f;
      float hvalB = (j < H_SZ) ? hB : 0.f;

      hA_s[g][j] = hvalA;  // own copies; in-wave DS ordering only
      hB_s[g][j] = hvalB;
      if (g == 1) {
        hs_b[((size_t)(b0 + u) * T_SZ + tA) * 64 + j] = f2bf(hvalA);
        hs_b[((size_t)(b0 + u) * T_SZ + tB) * 64 + j] = f2bf(hvalB);
      }
    }
  }
}

// ------------------------------------------------------------ K3: out GEMM
// out(32768 x 513, fp32) = hs_b(32768 x 64, bf16, k-padded) @ Wout^T + b_out.
// Wf_out (67,584 B) staged ONCE into LDS at kernel start (16 full 4096B rounds
// + one 2048B round by waves 0-1), then the nt loop reads LDS -> removes all
// per-lane L2 latency from the loop; kernel becomes write-bound (67MB fp32).
__global__ __launch_bounds__(256, 2) void gemm_out_mfma(
    const unsigned short* __restrict__ hs_b,
    const unsigned short* __restrict__ Wf, const float* __restrict__ bout,
    float* __restrict__ out) {
  int tid = threadIdx.x;
  int wave = tid >> 6;
  int lane = tid & 63;
  int m0 = blockIdx.x * 64 + wave * 16;
  int arow = lane & 15;  // m within tile
  int kg = lane >> 4;
  __shared__ __align__(16) unsigned short wbuf[NF_OUT * 8];  // 67,584 B

  {
    const char* src = (const char*)Wf;
    char* dst = (char*)wbuf;
#pragma unroll
    for (int q = 0; q < 16; q++)
      gll16(src + q * 4096 + tid * 16, dst + q * 4096 + wave * 1024);
    if (wave < 2) gll16(src + 65536 + tid * 16, dst + 65536 + wave * 1024);
  }

  const short8* Af = (const short8*)(hs_b + (size_t)(m0 + arow) * 64);
  short8 af0 = Af[kg];      // k = kg*8
  short8 af1 = Af[4 + kg];  // k = 32 + kg*8
  float* orow = out + (size_t)(m0 + arow) * F_SZ;
  __syncthreads();  // drain staging (implicit vmcnt(0)) before LDS reads

  const short8* bb = (const short8*)wbuf;
#pragma unroll
  for (int nt = 0; nt < 33; nt++) {
    short8 bf0 = bb[nt * 64 + lane];
    short8 bf1 = bb[(33 + nt) * 64 + lane];
    f32x4 acc = (f32x4){0.f, 0.f, 0.f, 0.f};
    acc = __builtin_amdgcn_mfma_f32_16x16x32_bf16(bf0, af0, acc, 0, 0, 0);
    acc = __builtin_amdgcn_mfma_f32_16x16x32_bf16(bf1, af1, acc, 0, 0, 0);
    if (nt < 32) {
      int f0 = nt * 16 + kg * 4;
      float4 bv = *(const float4*)&bout[f0];
      float4 o = make_float4(acc[0] + bv.x, acc[1] + bv.y, acc[2] + bv.z,
                             acc[3] + bv.w);
      *(float4*)(orow + f0) = o;  // rows 4B-aligned; HW handles unaligned x4
    } else if (kg == 0) {
      orow[512] = acc[0] + bout[512];  // nt=32: only f=512 real
    }
  }
}

extern "C" void kernel_launch(void* const* d_in, const int* in_sizes, int n_in,
                              void* d_out, int out_size, void* d_ws,
                              size_t ws_size, hipStream_t stream) {
  const float* x = (const float*)d_in[0];
  const float* Wih = (const float*)d_in[1];
  const float* Whh = (const float*)d_in[2];
  const float* bih = (const float*)d_in[3];
  const float* bhh = (const float*)d_in[4];
  const float* Wout = (const float*)d_in[5];
  const float* bout = (const float*)d_in[6];
  float* out = (float*)d_out;

  // ws layout (17.6 MB):
  //   xg_b   : bf16 [32768][200]   13,107,200 B @ 0
  //   hs_b   : bf16 [32768][64]     4,194,304 B @ 13,107,200
  //   Wf_ih  : 17*13*64 frags         226,304 B @ 17,301,504
  //   Wf_out : 2*33*64 frags           67,584 B @ 17,527,808
  unsigned short* xg_b = (unsigned short*)d_ws;
  unsigned short* hs_b = (unsigned short*)((char*)d_ws + 13107200);
  unsigned short* Wf_ih = (unsigned short*)((char*)d_ws + 17301504);
  unsigned short* Wf_out = (unsigned short*)((char*)d_ws + 17527808);

  conv_weights<<<(NF_IH + NF_OUT + 255) / 256, 256, 0, stream>>>(Wih, Wout,
                                                                 Wf_ih, Wf_out);

  gemm_xg_mfma<<<M_SZ / 64, 256, 0, stream>>>(x, Wf_ih, bih, xg_b);

  lstm_rec<<<T_SZ / 2, 256, 0, stream>>>(xg_b, Whh, bhh, hs_b);

  gemm_out_mfma<<<M_SZ / 64, 256, 0, stream>>>(hs_b, Wf_out, bout, out);
}

// Round 8
// 192.614 us; speedup vs baseline: 1.2740x; 1.0642x over previous
//
#include <hip/hip_runtime.h>
#include <hip/hip_bf16.h>

// Problem: lstm_20169166422798
// x:(64,512,513) W_ih:(200,513) W_hh:(200,50) b_ih:(200) b_hh:(200)
// W_out:(513,50) b_out:(513)  -> out:(64,512,513) fp32

#define B_SZ 64
#define T_SZ 512
#define F_SZ 513
#define H_SZ 50
#define G_SZ 200            // 4*H
#define M_SZ (B_SZ * T_SZ)  // 32768

typedef __attribute__((ext_vector_type(8))) short short8;   // bf16x8 MFMA frag
typedef __attribute__((ext_vector_type(4))) float f32x4;    // MFMA acc
typedef __attribute__((ext_vector_type(2))) float f32x2;    // packed-FMA pair

__device__ __forceinline__ float bf2f(unsigned short u) {
  unsigned int v = ((unsigned int)u) << 16;
  return __builtin_bit_cast(float, v);
}
__device__ __forceinline__ unsigned short f2bf(float f) {
  unsigned int b = __builtin_bit_cast(unsigned int, f);
  unsigned int r = b + 0x7FFFu + ((b >> 16) & 1u);
  return (unsigned short)(r >> 16);
}

// Anti-rematerialization pin (r3/r4): keeps loop-invariant weights resident.
__device__ __forceinline__ void pin2(f32x2& v) {
  double d = __builtin_bit_cast(double, v);
  asm volatile("" : "+v"(d));
  v = __builtin_bit_cast(f32x2, d);
}
__device__ __forceinline__ void pin1(float& v) { asm volatile("" : "+v"(v)); }

// async global->LDS; LDS dest = wave-uniform base + lane*size.
__device__ __forceinline__ void gll16(const void* g, void* l) {
  __builtin_amdgcn_global_load_lds(
      (const __attribute__((address_space(1))) unsigned int*)g,
      (__attribute__((address_space(3))) unsigned int*)l, 16, 0, 0);
}
__device__ __forceinline__ void gll4(const void* g, void* l) {
  __builtin_amdgcn_global_load_lds(
      (const __attribute__((address_space(1))) unsigned int*)g,
      (__attribute__((address_space(3))) unsigned int*)l, 4, 0, 0);
}

// --------------- K0w: W_ih and W_out -> bf16 MFMA fragments (consumption order)
// Wf_ih[((t*13+nt)*64+lane)] : n=nt*16+(lane&15), k=t*32+(lane>>4)*8+j, t=0..16
// Wf_out[((t*33+nt)*64+lane)]: n=nt*16+(lane&15), k=t*32+(lane>>4)*8+j, t=0..1
#define NF_IH (17 * 13 * 64)
#define NF_OUT (2 * 33 * 64)
__global__ __launch_bounds__(256) void conv_weights(
    const float* __restrict__ Wih, const float* __restrict__ Wout,
    unsigned short* __restrict__ Wf_ih, unsigned short* __restrict__ Wf_out) {
  int idx = blockIdx.x * 256 + threadIdx.x;
  if (idx < NF_IH) {
    int lane = idx & 63;
    int nt = (idx >> 6) % 13;
    int t = idx / (13 * 64);
    int n = nt * 16 + (lane & 15);
    int k0 = t * 32 + (lane >> 4) * 8;
    short8 v;
#pragma unroll
    for (int j = 0; j < 8; j++) {
      int k = k0 + j;
      v[j] = (n < G_SZ && k < F_SZ) ? (short)f2bf(Wih[(size_t)n * F_SZ + k])
                                    : (short)0;
    }
    *(short8*)(Wf_ih + (size_t)idx * 8) = v;
  } else if (idx < NF_IH + NF_OUT) {
    int id2 = idx - NF_IH;
    int lane = id2 & 63;
    int nt = (id2 >> 6) % 33;
    int t = id2 / (33 * 64);
    int n = nt * 16 + (lane & 15);
    int k0 = t * 32 + (lane >> 4) * 8;
    short8 v;
#pragma unroll
    for (int j = 0; j < 8; j++) {
      int k = k0 + j;
      v[j] = (n < F_SZ && k < H_SZ) ? (short)f2bf(Wout[(size_t)n * H_SZ + k])
                                    : (short)0;
    }
    *(short8*)(Wf_out + (size_t)id2 * 8) = v;
  }
}

// ---------------------------------------------------------------- K1: xg GEMM
// xg(32768 x 200, bf16) = x(32768 x 513, fp32, cvt in-register) @ W_ih^T + bih.
// Both operands go through the async global_load_lds queue (double-buffered,
// one barrier per t whose implicit vmcnt(0) drain is the sync): Wf slab 13KB
// (gll16 linear) + x slab 8KB (gll4, PRE-SWIZZLED per-lane sources so the
// stride-128B ds_read_b128 consumption is bank-minimal; swizzle on both sides,
// rule 21).  LDS map: dword p holds x[brow0+(p>>5)][t*32+((p&31)^(((p>>5)&7)<<2))].
// r7 BUG FIX: the read offset used arow (0..15) as the LDS row -- every wave
// read wave-0's rows (absmax 1.67).  Correct row = wave*16 + arow.
#define TSLAB 13312  // Wf: 13 frags * 64 lanes * 16B
__global__ __launch_bounds__(256, 2) void gemm_xg_mfma(
    const float* __restrict__ x, const unsigned short* __restrict__ Wf,
    const float* __restrict__ bih, unsigned short* __restrict__ xg) {
  int tid = threadIdx.x;
  int wave = tid >> 6;
  int lane = tid & 63;
  int m0 = blockIdx.x * 64 + wave * 16;
  int brow0 = blockIdx.x * 64;
  int arow = lane & 15;  // m within tile
  int kg = lane >> 4;
  __shared__ __align__(16) unsigned short bbuf[2][TSLAB / 2];  // 2 x 13,312 B
  __shared__ __align__(16) float xbuf[2][2048];                // 2 x 8,192 B

  f32x4 acc[13];
#pragma unroll
  for (int nt = 0; nt < 13; nt++) acc[nt] = (f32x4){0.f, 0.f, 0.f, 0.f};

  auto stage = [&](int pb, int t) {
    const char* wsrc = (const char*)Wf + (size_t)t * TSLAB;
    char* wdst = (char*)&bbuf[pb][0];
    gll16(wsrc + 0 * 4096 + tid * 16, wdst + 0 * 4096 + wave * 1024);
    gll16(wsrc + 1 * 4096 + tid * 16, wdst + 1 * 4096 + wave * 1024);
    gll16(wsrc + 2 * 4096 + tid * 16, wdst + 2 * 4096 + wave * 1024);
    if (wave == 0) gll16(wsrc + 12288 + lane * 16, wdst + 12288);
    if (t < 16) {
      // x slab t: rows brow0..brow0+63, bytes [t*128, t*128+128) of each row.
      // physical dword p = q*256+tid; row r = p>>5; col c = (p&31)^((r&7)<<2)
      const char* xt = (const char*)x + (size_t)brow0 * (F_SZ * 4) +
                       (size_t)t * 128;
      char* xdst = (char*)&xbuf[pb][0];
#pragma unroll
      for (int q = 0; q < 8; q++) {
        int p = q * 256 + tid;
        int r = p >> 5;
        int c4 = (((p & 31) ^ ((r & 7) << 2))) << 2;
        gll4(xt + (size_t)r * (F_SZ * 4) + c4, xdst + q * 1024 + wave * 256);
      }
    }
  };

  // lane's logical x bytes: row*128 + kg*32 (+16), row = wave*16+arow (r7 fix);
  // swizzled physical offset (note (row&7) == (arow&7)):
  int xrow = wave * 16 + arow;
  int xb0 = (xrow * 128 + kg * 32) ^ ((xrow & 7) << 4);

  // prologue: stage t=0; scalar x tail (k=512) per m-row
  stage(0, 0);
  float xtail = x[(size_t)(m0 + arow) * F_SZ + 512];
  __syncthreads();  // implicit vmcnt(0)+lgkm drain: buffer 0 ready

#pragma unroll 1
  for (int t = 0; t < 16; ++t) {
    int pb = t & 1;
    stage(pb ^ 1, t + 1);  // async into other buffer; drained by end barrier
    const char* xl = (const char*)&xbuf[pb][0];
    f32x4 lo = *(const f32x4*)(xl + xb0);
    f32x4 hi = *(const f32x4*)(xl + (xb0 ^ 16));
    short8 af;
#pragma unroll
    for (int jj = 0; jj < 4; jj++) af[jj] = (short)f2bf(lo[jj]);
#pragma unroll
    for (int jj = 0; jj < 4; jj++) af[4 + jj] = (short)f2bf(hi[jj]);
    const short8* bb = (const short8*)&bbuf[pb][0];
#pragma unroll
    for (int nt = 0; nt < 13; nt++) {
      short8 bf = bb[nt * 64 + lane];
      acc[nt] = __builtin_amdgcn_mfma_f32_16x16x32_bf16(bf, af, acc[nt], 0, 0, 0);
    }
    __syncthreads();  // staging(t+1) landed; buffer pb free next iter
  }
  // epilogue t=16 (k=512..543; only k=512 real, Wf zero-padded): slab in bbuf[0]
  {
    short8 af = (short8){0, 0, 0, 0, 0, 0, 0, 0};
    if (kg == 0) af[0] = (short)f2bf(xtail);
    const short8* bb = (const short8*)&bbuf[0][0];
#pragma unroll
    for (int nt = 0; nt < 13; nt++) {
      short8 bf = bb[nt * 64 + lane];
      acc[nt] = __builtin_amdgcn_mfma_f32_16x16x32_bf16(bf, af, acc[nt], 0, 0, 0);
    }
  }

  unsigned short* xrowp = xg + (size_t)(m0 + arow) * G_SZ;
#pragma unroll
  for (int nt = 0; nt < 13; nt++) {
    int nb = nt * 16 + kg * 4;
    if (nt < 12 || kg < 2) {  // n < 200
      float4 bi = *(const float4*)&bih[nb];
      ushort4 o;
      o.x = f2bf(acc[nt][0] + bi.x);
      o.y = f2bf(acc[nt][1] + bi.y);
      o.z = f2bf(acc[nt][2] + bi.z);
      o.w = f2bf(acc[nt][3] + bi.w);
      *(ushort4*)(xrowp + nb) = o;
    }
  }
}

// ------------------------------------------------------------- K2: recurrence
__device__ __forceinline__ float sig_f(float v) {
  return 1.0f / (1.0f + __expf(-v));
}
__device__ __forceinline__ float tanh_f(float v) {
  return 2.0f / (1.0f + __expf(-2.0f * v)) - 1.0f;
}

// EXACT r5 structure (measured 47.0us): 4-wave block per t, grid 512 = 2
// blocks/CU.  Pinned packed weights, one barrier/step, gact parity
// double-buffer, 8-step xg prefetch.
__global__ __launch_bounds__(256, 2) void lstm_rec(
    const unsigned short* __restrict__ xg, const float* __restrict__ Whh,
    const float* __restrict__ bhh, unsigned short* __restrict__ hs_b) {
  int t = blockIdx.x;
  int g = threadIdx.x >> 6;   // gate 0..3 (i,f,g,o)
  int j = threadIdx.x & 63;
  int jc = (j < H_SZ) ? j : (H_SZ - 1);
  __shared__ __align__(16) float h_s[4][64];     // per-wave private h copy
  __shared__ __align__(16) float gact[2][4][64]; // double-buffered activations

  int grow = g * H_SZ + jc;
  float bh = bhh[grow];
  pin1(bh);
  f32x2 w2[25];
#pragma unroll
  for (int k = 0; k < 25; k++) {
    w2[k] = *(const f32x2*)(Whh + (size_t)grow * H_SZ + 2 * k);
    pin2(w2[k]);  // non-rematerializable: resident for all 64 steps
  }

  h_s[g][j] = 0.f;
  float c = 0.f;

  const size_t bstr = (size_t)T_SZ * G_SZ;
  const unsigned short* xp = xg + (size_t)t * G_SZ + grow;

  // 8-step-deep prefetch of this wave's gate stream (1 ushort per step)
  unsigned short rA[4], rB[4];
#pragma unroll
  for (int q = 0; q < 4; q++) rA[q] = xp[(size_t)q * bstr];
#pragma unroll
  for (int q = 0; q < 4; q++) rB[q] = xp[(size_t)(4 + q) * bstr];

#pragma unroll 1
  for (int b0 = 0; b0 < B_SZ; b0 += 8) {
    float xf[8];
#pragma unroll
    for (int q = 0; q < 4; q++) xf[q] = bf2f(rA[q]);
    if (b0 + 8 < B_SZ) {
#pragma unroll
      for (int q = 0; q < 4; q++) rA[q] = xp[(size_t)(b0 + 8 + q) * bstr];
    }
#pragma unroll
    for (int q = 0; q < 4; q++) xf[4 + q] = bf2f(rB[q]);
    if (b0 + 12 < B_SZ) {
#pragma unroll
      for (int q = 0; q < 4; q++) rB[q] = xp[(size_t)(b0 + 12 + q) * bstr];
    }

#pragma unroll
    for (int u = 0; u < 8; u++) {  // static u: xf index and gact parity fold
      f32x2 aa = (f32x2){xf[u] + bh, 0.f};
      f32x2 ab = (f32x2){0.f, 0.f};

      // h broadcast: 12 x b128 + 1 x b64, wave-uniform addresses
      const float4* h4 = (const float4*)h_s[g];
#pragma unroll
      for (int kq = 0; kq < 12; kq++) {
        float4 hv = h4[kq];
        aa = __builtin_elementwise_fma((f32x2){hv.x, hv.y}, w2[2 * kq], aa);
        ab = __builtin_elementwise_fma((f32x2){hv.z, hv.w}, w2[2 * kq + 1], ab);
      }
      {
        f32x2 hl = *(const f32x2*)(h_s[g] + 48);
        aa = __builtin_elementwise_fma(hl, w2[24], aa);
      }
      float av = (aa[0] + ab[0]) + (aa[1] + ab[1]);

      gact[u & 1][g][j] = (g == 2) ? tanh_f(av) : sig_f(av);
      __syncthreads();  // the only barrier per step

      float iv = gact[u & 1][0][jc];
      float fv = gact[u & 1][1][jc];
      float gv = gact[u & 1][2][jc];
      float ov = gact[u & 1][3][jc];
      c = fmaf(fv, c, iv * gv);
      float h = ov * tanh_f(c);
      float hval = (j < H_SZ) ? h : 0.f;

      h_s[g][j] = hval;  // own copy; in-wave DS ordering only
      if (g == 1)
        hs_b[((size_t)(b0 + u) * T_SZ + t) * 64 + j] = f2bf(hval);
    }
  }
}

// ------------------------------------------------------------ K3: out GEMM
// out(32768 x 513, fp32) = hs_b(32768 x 64, bf16, k-padded) @ Wout^T + b_out.
// Wf_out (67,584 B) staged ONCE into LDS; nt loop reads LDS; write-bound.
__global__ __launch_bounds__(256, 2) void gemm_out_mfma(
    const unsigned short* __restrict__ hs_b,
    const unsigned short* __restrict__ Wf, const float* __restrict__ bout,
    float* __restrict__ out) {
  int tid = threadIdx.x;
  int wave = tid >> 6;
  int lane = tid & 63;
  int m0 = blockIdx.x * 64 + wave * 16;
  int arow = lane & 15;  // m within tile
  int kg = lane >> 4;
  __shared__ __align__(16) unsigned short wbuf[NF_OUT * 8];  // 67,584 B

  {
    const char* src = (const char*)Wf;
    char* dst = (char*)wbuf;
#pragma unroll
    for (int q = 0; q < 16; q++)
      gll16(src + q * 4096 + tid * 16, dst + q * 4096 + wave * 1024);
    if (wave < 2) gll16(src + 65536 + tid * 16, dst + 65536 + wave * 1024);
  }

  const short8* Af = (const short8*)(hs_b + (size_t)(m0 + arow) * 64);
  short8 af0 = Af[kg];      // k = kg*8
  short8 af1 = Af[4 + kg];  // k = 32 + kg*8
  float* orow = out + (size_t)(m0 + arow) * F_SZ;
  __syncthreads();  // drain staging (implicit vmcnt(0)) before LDS reads

  const short8* bb = (const short8*)wbuf;
#pragma unroll
  for (int nt = 0; nt < 33; nt++) {
    short8 bf0 = bb[nt * 64 + lane];
    short8 bf1 = bb[(33 + nt) * 64 + lane];
    f32x4 acc = (f32x4){0.f, 0.f, 0.f, 0.f};
    acc = __builtin_amdgcn_mfma_f32_16x16x32_bf16(bf0, af0, acc, 0, 0, 0);
    acc = __builtin_amdgcn_mfma_f32_16x16x32_bf16(bf1, af1, acc, 0, 0, 0);
    if (nt < 32) {
      int f0 = nt * 16 + kg * 4;
      float4 bv = *(const float4*)&bout[f0];
      float4 o = make_float4(acc[0] + bv.x, acc[1] + bv.y, acc[2] + bv.z,
                             acc[3] + bv.w);
      *(float4*)(orow + f0) = o;  // rows 4B-aligned; HW handles unaligned x4
    } else if (kg == 0) {
      orow[512] = acc[0] + bout[512];  // nt=32: only f=512 real
    }
  }
}

extern "C" void kernel_launch(void* const* d_in, const int* in_sizes, int n_in,
                              void* d_out, int out_size, void* d_ws,
                              size_t ws_size, hipStream_t stream) {
  const float* x = (const float*)d_in[0];
  const float* Wih = (const float*)d_in[1];
  const float* Whh = (const float*)d_in[2];
  const float* bih = (const float*)d_in[3];
  const float* bhh = (const float*)d_in[4];
  const float* Wout = (const float*)d_in[5];
  const float* bout = (const float*)d_in[6];
  float* out = (float*)d_out;

  // ws layout (17.6 MB):
  //   xg_b   : bf16 [32768][200]   13,107,200 B @ 0
  //   hs_b   : bf16 [32768][64]     4,194,304 B @ 13,107,200
  //   Wf_ih  : 17*13*64 frags         226,304 B @ 17,301,504
  //   Wf_out : 2*33*64 frags           67,584 B @ 17,527,808
  unsigned short* xg_b = (unsigned short*)d_ws;
  unsigned short* hs_b = (unsigned short*)((char*)d_ws + 13107200);
  unsigned short* Wf_ih = (unsigned short*)((char*)d_ws + 17301504);
  unsigned short* Wf_out = (unsigned short*)((char*)d_ws + 17527808);

  conv_weights<<<(NF_IH + NF_OUT + 255) / 256, 256, 0, stream>>>(Wih, Wout,
                                                                 Wf_ih, Wf_out);

  gemm_xg_mfma<<<M_SZ / 64, 256, 0, stream>>>(x, Wf_ih, bih, xg_b);

  lstm_rec<<<T_SZ, 256, 0, stream>>>(xg_b, Whh, bhh, hs_b);

  gemm_out_mfma<<<M_SZ / 64, 256, 0, stream>>>(hs_b, Wf_out, bout, out);
}